// Round 7
// baseline (145.304 us; speedup 1.0000x reference)
//
#include <hip/hip_runtime.h>
#include <math.h>

// Problem constants (match reference)
#define T_LEN 4096
#define FIR_L 513
#define N_PHA 10
#define N_AMP 10
#define N_BANDS 20
#define N_BINS 18
#define BC 64            // B*C = 4*16

typedef __attribute__((ext_vector_type(8))) short short8;
typedef __attribute__((ext_vector_type(4))) float f32x4;

// Interleaved-complex skewed addresses (float index of re; im at +1).
// Extents: ZA(4095)+2 = 8702 -> z region 8704 floats; TA(1023)+2 = 2174 -> 2176.
#define ZA(i) (((i) << 1) + ((((i) >> 4)) << 1))
#define TA(m) (((m) << 1) + ((((m) >> 4)) << 1))

// float -> bf16 round-to-nearest-even
static __device__ __forceinline__ unsigned short f2bf(float x) {
    unsigned u = __float_as_uint(x);
    unsigned r = u + 0x7FFFu + ((u >> 16) & 1u);
    return (unsigned short)(r >> 16);
}

// storage index -> frequency after radix-4 DIF (base-4 digit reversal)
static __device__ __forceinline__ int digitrev12(int p) {
    unsigned rr = __brev((unsigned)p) >> 20;               // 12-bit bit reversal
    rr = ((rr & 0x555u) << 1) | ((rr & 0xAAAu) >> 1);      // swap bit pairs
    return (int)rr;
}

// Forward radix-4 DIF, natural -> base-4 digit-reversed. tw[m]=(c,s) m<1024.
static __device__ __forceinline__ void fft_fwd6(float* z, const float* tw, int tid) {
    for (int s = 0; s < 6; ++s) {
        const int hl = 10 - 2 * s;
        const int h  = 1 << hl;
#pragma unroll
        for (int r = 0; r < 4; ++r) {
            const int u  = tid + (r << 8);
            const int k  = u & (h - 1);
            const int g  = u >> hl;
            const int i0 = (g << (hl + 2)) + k;
            const int m1 = k << (2 * s);                 // < 1024
            const float2 w1 = *(const float2*)&tw[TA(m1)];
            const float c1 = w1.x, s1 = w1.y;
            const float s2 = 2.0f * s1 * c1;             // double angle
            const float c2 = fmaf(-2.0f * s1, s1, 1.0f);
            const float c3 = c1 * c2 - s1 * s2;          // angle sum
            const float s3 = s1 * c2 + c1 * s2;

            float2 a = *(const float2*)&z[ZA(i0)];
            float2 b = *(const float2*)&z[ZA(i0 + h)];
            float2 c = *(const float2*)&z[ZA(i0 + 2 * h)];
            float2 d = *(const float2*)&z[ZA(i0 + 3 * h)];

            const float t0r = a.x + c.x, t0i = a.y + c.y;
            const float t1r = a.x - c.x, t1i = a.y - c.y;
            const float t2r = b.x + d.x, t2i = b.y + d.y;
            const float t3r = b.x - d.x, t3i = b.y - d.y;

            const float y0r = t0r + t2r,  y0i = t0i + t2i;
            const float u1r = t1r + t3i, u1i = t1i - t3r;   // t1 - i*t3
            const float u2r = t0r - t2r, u2i = t0i - t2i;
            const float u3r = t1r - t3i, u3i = t1i + t3r;   // t1 + i*t3
            const float y1r = u1r * c1 + u1i * s1, y1i = u1i * c1 - u1r * s1;
            const float y2r = u2r * c2 + u2i * s2, y2i = u2i * c2 - u2r * s2;
            const float y3r = u3r * c3 + u3i * s3, y3i = u3i * c3 - u3r * s3;

            *(float2*)&z[ZA(i0)]         = make_float2(y0r, y0i);
            *(float2*)&z[ZA(i0 + h)]     = make_float2(y1r, y1i);
            *(float2*)&z[ZA(i0 + 2 * h)] = make_float2(y2r, y2i);
            *(float2*)&z[ZA(i0 + 3 * h)] = make_float2(y3r, y3i);
        }
        __syncthreads();
    }
}

// Inverse radix-4 DIT, base-4 digit-reversed -> natural (unscaled).
static __device__ __forceinline__ void fft_inv6(float* z, const float* tw, int tid) {
    for (int s = 0; s < 6; ++s) {
        const int hl = 2 * s;
        const int L  = 1 << hl;
#pragma unroll
        for (int r = 0; r < 4; ++r) {
            const int u  = tid + (r << 8);
            const int k  = u & (L - 1);
            const int g  = u >> hl;
            const int i0 = (g << (hl + 2)) + k;
            const int m1 = k << (10 - hl);               // < 1024
            const float2 w1 = *(const float2*)&tw[TA(m1)];
            const float c1 = w1.x, s1 = w1.y;
            const float s2 = 2.0f * s1 * c1;
            const float c2 = fmaf(-2.0f * s1, s1, 1.0f);
            const float c3 = c1 * c2 - s1 * s2;
            const float s3 = s1 * c2 + c1 * s2;

            float2 a = *(const float2*)&z[ZA(i0)];
            float2 b = *(const float2*)&z[ZA(i0 + L)];
            float2 c = *(const float2*)&z[ZA(i0 + 2 * L)];
            float2 d = *(const float2*)&z[ZA(i0 + 3 * L)];

            const float tbr = b.x * c1 - b.y * s1, tbi = b.y * c1 + b.x * s1;
            const float tcr = c.x * c2 - c.y * s2, tci = c.y * c2 + c.x * s2;
            const float tdr = d.x * c3 - d.y * s3, tdi = d.y * c3 + d.x * s3;

            const float y0r = a.x + tbr + tcr + tdr;
            const float y0i = a.y + tbi + tci + tdi;
            const float y1r = a.x - tbi - tcr + tdi;
            const float y1i = a.y + tbr - tci - tdr;
            const float y2r = a.x - tbr + tcr - tdr;
            const float y2i = a.y - tbi + tci - tdi;
            const float y3r = a.x + tbi - tcr - tdi;
            const float y3i = a.y - tbr - tci + tdr;

            *(float2*)&z[ZA(i0)]         = make_float2(y0r, y0i);
            *(float2*)&z[ZA(i0 + L)]     = make_float2(y1r, y1i);
            *(float2*)&z[ZA(i0 + 2 * L)] = make_float2(y2r, y2i);
            *(float2*)&z[ZA(i0 + 3 * L)] = make_float2(y3r, y3i);
        }
        __syncthreads();
    }
}

// ---------------------------------------------------------------------------
// Precompute: blocks 0..63 -> X[bc]; blocks 64..83 -> Hf[band] (corr kernel
// h[n]=f[256-n] circular). Spectra stored in digit-reversed order.
// ---------------------------------------------------------------------------
__global__ __launch_bounds__(256) void spectral_pre(
    const float* __restrict__ x,      // (BC, T)
    const float* __restrict__ filt,   // (20, 513)
    float2* __restrict__ Xs,          // (BC, 4096)
    float2* __restrict__ Hs)          // (20, 4096)
{
    __shared__ float smem[10880];
    __shared__ float fb[FIR_L];
    float* z  = smem;
    float* tw = smem + 8704;

    const int tid = threadIdx.x;
    const int b   = blockIdx.x;

    for (int m = tid; m < 1024; m += 256) {
        float ang = (float)m * (6.283185307179586f / 4096.0f);
        float s, c;
        sincosf(ang, &s, &c);
        tw[TA(m)]     = c;
        tw[TA(m) + 1] = s;
    }

    if (b < BC) {
        const float* xrow = x + b * T_LEN;
        for (int i = tid; i < 4096; i += 256)
            *(float2*)&z[ZA(i)] = make_float2(xrow[i], 0.0f);
    } else {
        const int band = b - BC;
        for (int i = tid; i < FIR_L; i += 256) fb[i] = filt[band * FIR_L + i];
        __syncthreads();
        for (int i = tid; i < 4096; i += 256) {
            float hv = 0.0f;
            if (i < 257)        hv = fb[256 - i];
            else if (i >= 3840) hv = fb[4352 - i];
            *(float2*)&z[ZA(i)] = make_float2(hv, 0.0f);
        }
    }
    __syncthreads();

    fft_fwd6(z, tw, tid);

    float2* dst = (b < BC) ? (Xs + b * 4096) : (Hs + (b - BC) * 4096);
    for (int i = tid; i < 4096; i += 256)
        dst[i] = *(const float2*)&z[ZA(i)];
}

// ---------------------------------------------------------------------------
// Main: per (bc, band-pair j/j+10): both corr signals are REAL -> pack
// corr_a + i*corr_b into ONE forward FFT, split via Hermitian symmetry,
// then two masked pointwise products and two inverse FFTs.
// ---------------------------------------------------------------------------
__global__ __launch_bounds__(256) void spectral_main(
    const float* __restrict__ x,          // (BC, T)
    const float* __restrict__ filt,       // (20, 513)
    const float2* __restrict__ Xs,        // (BC, 4096)
    const float2* __restrict__ Hs,        // (20, 4096)
    float* __restrict__ pha,              // (BC, 10, T) fp32
    unsigned short* __restrict__ amp_bf)  // (BC, 10, T) bf16 bits
{
    __shared__ float smem[10880];   // z [0,8704), tw [8704,10880)
    __shared__ float xe[512];       // x[0..255] | x[3840..4095]
    __shared__ float fb0[FIR_L];    // band j (phase)
    __shared__ float fb1[FIR_L];    // band j+10 (amp)
    float* z  = smem;
    float* tw = smem + 8704;

    const int tid = threadIdx.x;
    const int bc  = blockIdx.x / N_PHA;
    const int j   = blockIdx.x % N_PHA;

    for (int m = tid; m < 1024; m += 256) {
        float ang = (float)m * (6.283185307179586f / 4096.0f);
        float s, c;
        sincosf(ang, &s, &c);
        tw[TA(m)]     = c;
        tw[TA(m) + 1] = s;
    }

    const float* xrow = x + bc * T_LEN;
    for (int i = tid; i < 512; i += 256)
        xe[i] = (i < 256) ? xrow[i] : xrow[3584 + i];
    for (int i = tid; i < FIR_L; i += 256) {
        fb0[i] = filt[j * FIR_L + i];
        fb1[i] = filt[(j + N_PHA) * FIR_L + i];
    }
    __syncthreads();

    // ---- boundary corrections for both bands (shared xe reads)
    float cfa = 0.0f, cfb = 0.0f, cta = 0.0f, ctb = 0.0f;
    for (int l = 0; l <= 255 - tid; ++l) {
        const float xv = xe[256 + tid + l];
        cfa = fmaf(fb0[l], xv, cfa);
        cfb = fmaf(fb1[l], xv, cfb);
    }
    for (int jj = 0; jj <= tid; ++jj) {
        const float xv = xe[jj];
        cta = fmaf(fb0[512 - tid + jj], xv, cta);
        ctb = fmaf(fb1[512 - tid + jj], xv, ctb);
    }

    // stage packed corr_a + i*corr_b (zero middle)
    for (int i = tid; i < 4096; i += 256)
        *(float2*)&z[ZA(i)] = make_float2(0.0f, 0.0f);
    *(float2*)&z[ZA(tid)]        = make_float2(-cfa, -cfb);
    *(float2*)&z[ZA(3840 + tid)] = make_float2(-cta, -ctb);
    __syncthreads();

    fft_fwd6(z, tw, tid);    // Z = Ca + i*Cb, digit-reversed

    // ---- pass 1: Hermitian split + pointwise products into registers
    const float2* Xrow = Xs + bc * 4096;
    const float2* H0r  = Hs + j * 4096;
    const float2* H1r  = Hs + (j + N_PHA) * 4096;
    float2 Pa[16], Pb[16];
#pragma unroll 1
    for (int r = 0; r < 16; ++r) {
        const int i  = tid + (r << 8);
        const int f  = digitrev12(i);
        const int g  = (4096 - f) & 4095;
        const int ir = digitrev12(g);
        const float2 Zs = *(const float2*)&z[ZA(i)];
        const float2 Zp = *(const float2*)&z[ZA(ir)];
        // A = spectrum of corr_a, B = spectrum of corr_b
        const float Ax = 0.5f * (Zs.x + Zp.x), Ay = 0.5f * (Zs.y - Zp.y);
        const float Bx = 0.5f * (Zs.y + Zp.y), By = 0.5f * (Zp.x - Zs.x);
        const float2 X  = Xrow[i];
        const float2 H0 = H0r[i];
        const float2 H1 = H1r[i];
        const float mf = (f == 0 || f == 2048) ? 1.0f : (f < 2048 ? 2.0f : 0.0f);
        Pa[r] = make_float2((X.x * H0.x - X.y * H0.y + Ax) * mf,
                            (X.x * H0.y + X.y * H0.x + Ay) * mf);
        Pb[r] = make_float2((X.x * H1.x - X.y * H1.y + Bx) * mf,
                            (X.x * H1.y + X.y * H1.x + By) * mf);
    }
    __syncthreads();   // all pair reads done before overwriting z

    // ---- band j (phase): inv FFT + atan2 emit
#pragma unroll
    for (int r = 0; r < 16; ++r)
        *(float2*)&z[ZA(tid + (r << 8))] = Pa[r];
    __syncthreads();
    fft_inv6(z, tw, tid);
    {
        float* dst = pha + (bc * N_PHA + j) * T_LEN;
        for (int i = tid; i < 4096; i += 256) {
            const float2 zz = *(const float2*)&z[ZA(i)];
            dst[i] = atan2f(zz.y, zz.x);         // 1/N scale cancels
        }
    }
    __syncthreads();   // emit reads done before overwriting z

    // ---- band j+10 (amplitude): inv FFT + |.| emit (bf16)
#pragma unroll
    for (int r = 0; r < 16; ++r)
        *(float2*)&z[ZA(tid + (r << 8))] = Pb[r];
    __syncthreads();
    fft_inv6(z, tw, tid);
    {
        const float inv_n = 1.0f / 4096.0f;
        unsigned short* dst = amp_bf + (bc * N_AMP + j) * T_LEN;
        for (int i = tid; i < 4096; i += 256) {
            const float2 zz = *(const float2*)&z[ZA(i)];
            dst[i] = f2bf(sqrtf(zz.x * zz.x + zz.y * zz.y) * inv_n);
        }
    }
}

// ---------------------------------------------------------------------------
// Kernel 2a: K-split x4. Each block: (bc,p) x quarter of T. 3-hot softmax +
// MFMA einsum; partial sums via global fp32 atomics (gsum zeroed by memset).
// ---------------------------------------------------------------------------
__global__ __launch_bounds__(256) void bin_mi_part(
    const float* __restrict__ pha,             // (BC, 10, T) fp32
    const unsigned short* __restrict__ amp_bf, // (BC, 10, T) bf16 bits
    float* __restrict__ gsum)                  // (640, 11*18)
{
    const int tid  = threadIdx.x;
    const int lane = tid & 63;
    const int wv   = tid >> 6;
    const int bcp  = blockIdx.x >> 2;          // (bc*10+p)
    const int part = blockIdx.x & 3;
    const int bc   = bcp / N_PHA;

    __shared__ unsigned int wbufW[4][18 * 68];
    __shared__ float psum[4][11][N_BINS];

    const float* phrow = pha + bcp * T_LEN;
    const unsigned short* arow = amp_bf + bc * N_AMP * T_LEN;

    const float PI_F  = 3.14159274101257324f;
    const float INVD  = 2.8647889756541160f;   // 9/pi
    const float DELTA = 0.34906585039886590f;  // 2pi/18
    const float C1    = 12.184696791468343f;   // DELTA^2 / 0.01
    const float C2    = 69.813170079773180f;   // 2*DELTA / 0.01

    const int m_ = lane & 15;
    const int q_ = lane >> 4;
    const int n_ = lane & 15;

    short8 zero8;
#pragma unroll
    for (int k = 0; k < 8; ++k) zero8[k] = 0;
    short8 ones8;
#pragma unroll
    for (int k = 0; k < 8; ++k) ones8[k] = (short)0x3F80;   // bf16 1.0

    f32x4 acc0 = {0.f, 0.f, 0.f, 0.f};
    f32x4 acc1 = {0.f, 0.f, 0.f, 0.f};

    const int base_t = part * 1024 + wv * 256;
    unsigned short* wh = (unsigned short*)&wbufW[wv][0];

    for (int chunk = 0; chunk < 2; ++chunk) {
        const int cb = base_t + chunk * 128;
        const float2 pp = *(const float2*)&phrow[cb + lane * 2];

        // prefetch A fragments (latency overlaps softmax)
        short8 af[4];
#pragma unroll
        for (int s = 0; s < 4; ++s) {
            const int tA = cb + s * 32 + q_ * 8;
            if (m_ < N_AMP)       af[s] = *(const short8*)(arow + m_ * T_LEN + tA);
            else if (m_ == N_AMP) af[s] = ones8;
            else                  af[s] = zero8;
        }

#pragma unroll
        for (int k = 0; k < N_BINS; ++k)
            wbufW[wv][k * 68 + lane] = 0u;

#pragma unroll
        for (int h = 0; h < 2; ++h) {
            const float ph = h ? pp.y : pp.x;
            float u  = (ph + PI_F) * INVD;
            float jf = floorf(u);
            float d  = (u - jf - 0.5f) * DELTA;
            int j0 = (int)jf;
            if (j0 >= N_BINS) j0 -= N_BINS;
            const int jm = (j0 == 0) ? N_BINS - 1 : j0 - 1;
            const int jp = (j0 == N_BINS - 1) ? 0 : j0 + 1;
            const float em = expf(-C1 - C2 * d);
            const float ep = expf(-C1 + C2 * d);
            const float inv = 1.0f / (1.0f + em + ep);
            wh[(j0 * 68 + lane) * 2 + h] = f2bf(inv);
            wh[(jm * 68 + lane) * 2 + h] = f2bf(em * inv);
            wh[(jp * 68 + lane) * 2 + h] = f2bf(ep * inv);
        }
        __builtin_amdgcn_wave_barrier();

#pragma unroll
        for (int s = 0; s < 4; ++s) {
            const int woff = s * 16 + q_ * 4;
            short8 bfrag0 = *(const short8*)&wbufW[wv][n_ * 68 + woff];
            short8 bfrag1 = (n_ < 2)
                ? *(const short8*)&wbufW[wv][(16 + n_) * 68 + woff]
                : zero8;
            acc0 = __builtin_amdgcn_mfma_f32_16x16x32_bf16(af[s], bfrag0, acc0, 0, 0, 0);
            acc1 = __builtin_amdgcn_mfma_f32_16x16x32_bf16(af[s], bfrag1, acc1, 0, 0, 0);
        }
        __builtin_amdgcn_wave_barrier();
    }

#pragma unroll
    for (int r = 0; r < 4; ++r) {
        const int m = q_ * 4 + r;
        if (m < 11) {
            psum[wv][m][n_] = acc0[r];
            if (n_ < 2) psum[wv][m][16 + n_] = acc1[r];
        }
    }
    __syncthreads();

    if (tid < 11 * N_BINS) {
        const int m = tid / N_BINS;
        const int k = tid % N_BINS;
        const float v = psum[0][m][k] + psum[1][m][k] + psum[2][m][k] + psum[3][m][k];
        atomicAdd(&gsum[bcp * 198 + tid], v);
    }
}

// ---------------------------------------------------------------------------
// Kernel 2b: finish — mean-amp -> p -> Tort MI.
// ---------------------------------------------------------------------------
__global__ __launch_bounds__(64) void mi_finish(
    const float* __restrict__ gsum,   // (640, 11*18)
    float* __restrict__ out)          // (BC, 10, 10)
{
    const int bcp = blockIdx.x;
    const int tid = threadIdx.x;
    const float* row = gsum + bcp * 198;

    if (tid < N_AMP) {
        float ma[N_BINS];
        float msum = 0.0f;
#pragma unroll
        for (int k = 0; k < N_BINS; ++k) {
            float m = row[tid * N_BINS + k] / (row[180 + k] + 1e-8f);
            ma[k] = m;
            msum += m;
        }
        const float inv = 1.0f / (msum + 1e-8f);
        float acc = 0.0f;
#pragma unroll
        for (int k = 0; k < N_BINS; ++k) {
            float pk = ma[k] * inv;
            acc = fmaf(pk, logf(pk + 1e-8f), acc);
        }
        const float logk = 2.89037175789124f;    // log(18)
        out[bcp * N_AMP + tid] = (logk + acc) / logk;
    }
}

extern "C" void kernel_launch(void* const* d_in, const int* in_sizes, int n_in,
                              void* d_out, int out_size, void* d_ws, size_t ws_size,
                              hipStream_t stream) {
    const float* x    = (const float*)d_in[0];   // (4,16,4096) f32
    const float* filt = (const float*)d_in[1];   // (20,513) f32
    float* out = (float*)d_out;                  // (4,16,10,10) f32

    // ws layout: pha fp32 | amp bf16 | Xspec | Hspec | gsum  (~19 MB)
    float* pha = (float*)d_ws;                               // BC*10*T fp32
    unsigned short* amp_bf = (unsigned short*)(pha + BC * N_PHA * T_LEN);
    float2* Xs = (float2*)(amp_bf + BC * N_AMP * T_LEN);     // BC*4096 cplx
    float2* Hs = Xs + BC * 4096;                             // 20*4096 cplx
    float* gsum = (float*)(Hs + N_BANDS * 4096);             // 640*198 f32

    hipMemsetAsync(gsum, 0, 640 * 198 * sizeof(float), stream);
    spectral_pre <<<BC + N_BANDS, 256, 0, stream>>>(x, filt, Xs, Hs);
    spectral_main<<<BC * N_PHA,   256, 0, stream>>>(x, filt, Xs, Hs, pha, amp_bf);
    bin_mi_part  <<<BC * N_PHA * 4, 256, 0, stream>>>(pha, amp_bf, gsum);
    mi_finish    <<<BC * N_PHA,   64, 0, stream>>>(gsum, out);
}